// Round 1
// baseline (452.067 us; speedup 1.0000x reference)
//
#include <hip/hip_runtime.h>

#define DEVINL __device__ __forceinline__

typedef _Float16 half8 __attribute__((ext_vector_type(8)));
typedef float f32x4 __attribute__((ext_vector_type(4)));
typedef float float4v __attribute__((ext_vector_type(4)));

static constexpr int kDIM = 1024;
static constexpr int kHEADS = 16;
static constexpr int kHD = 64;
static constexpr int kBS = 4;
static constexpr int kSQ = 2048;
static constexpr int kSK = 2048;
static constexpr int kMTOT = kBS * kSQ;  // 8192

DEVINL void async_copy16(void* lds, const void* g) {
  __builtin_amdgcn_global_load_lds(
      (__attribute__((address_space(1))) unsigned int*)(g),
      (__attribute__((address_space(3))) unsigned int*)(lds), 16, 0, 0);
}

// ---------------- mask bit-packing: mask[b][q][k] int32 -> bit per key ----
__global__ void pack_mask_kernel(const int* __restrict__ mask,
                                 unsigned* __restrict__ bits) {
  int t = blockIdx.x * blockDim.x + threadIdx.x;  // word index
  const int* p = mask + (size_t)t * 32;
  unsigned w = 0;
#pragma unroll
  for (int j = 0; j < 32; ++j) w |= (p[j] != 0 ? 1u : 0u) << j;
  bits[t] = w;
}

// ---------------- f32 -> f16 convert (weights) ---------------------------
__global__ void cvt_f32_f16_kernel(const float* __restrict__ src,
                                   _Float16* __restrict__ dst, int n) {
  int i = (blockIdx.x * blockDim.x + threadIdx.x) * 8;
  if (i >= n) return;
  float4v a0 = *(const float4v*)(src + i);
  float4v a1 = *(const float4v*)(src + i + 4);
  half8 h;
  h[0] = (_Float16)a0[0]; h[1] = (_Float16)a0[1];
  h[2] = (_Float16)a0[2]; h[3] = (_Float16)a0[3];
  h[4] = (_Float16)a1[0]; h[5] = (_Float16)a1[1];
  h[6] = (_Float16)a1[2]; h[7] = (_Float16)a1[3];
  *(half8*)(dst + i) = h;
}

// ---------------- GEMM: C[M,N] = A[M,K] @ B[N,K]^T + bias -----------------
// 128x128 tile, BK=32, 4 waves (2x2), m97 structure + source-side XOR swizzle.
template <bool A_F32, bool OUT_F16>
__launch_bounds__(256, 2)
__global__ void gemm_bt_kernel(const void* __restrict__ Aptr,
                               const _Float16* __restrict__ B,
                               const float* __restrict__ bias,
                               void* __restrict__ Cptr, int M, int N, int K) {
  __shared__ __align__(16) _Float16 As[128 * 32];
  __shared__ __align__(16) _Float16 Bs[128 * 32];
  const int tid = threadIdx.x;
  const int lane = tid & 63;
  const int w = tid >> 6;
  const int wr = w >> 1, wc = w & 1;
  const int bm0 = blockIdx.y * 128;
  const int bn0 = blockIdx.x * 128;
  const int c16 = lane & 15;
  const int hi4 = lane >> 4;

  f32x4 acc[4][4] = {};

  for (int k0 = 0; k0 < K; k0 += 32) {
    __syncthreads();
    // ---- stage A tile [128][32] f16, rows 64B, seg xor (row&3) -----------
    if (A_F32) {
      const float* A32 = (const float*)Aptr;
#pragma unroll
      for (int i = 0; i < 2; ++i) {
        int c = i * 256 + tid;
        int row = c >> 2, seg = c & 3;
        int gseg = seg ^ (row & 3);
        const float* src = A32 + (size_t)(bm0 + row) * K + k0 + gseg * 8;
        float4v a0 = *(const float4v*)src;
        float4v a1 = *(const float4v*)(src + 4);
        half8 h;
        h[0] = (_Float16)a0[0]; h[1] = (_Float16)a0[1];
        h[2] = (_Float16)a0[2]; h[3] = (_Float16)a0[3];
        h[4] = (_Float16)a1[0]; h[5] = (_Float16)a1[1];
        h[6] = (_Float16)a1[2]; h[7] = (_Float16)a1[3];
        *(half8*)((char*)As + c * 16) = h;
      }
    } else {
      const _Float16* A16 = (const _Float16*)Aptr;
#pragma unroll
      for (int i = 0; i < 2; ++i) {
        int c = i * 256 + tid;
        int row = c >> 2, seg = c & 3;
        int gseg = seg ^ (row & 3);
        async_copy16((char*)As + i * 4096 + w * 1024,
                     A16 + (size_t)(bm0 + row) * K + k0 + gseg * 8);
      }
    }
    // ---- stage B tile ----------------------------------------------------
#pragma unroll
    for (int i = 0; i < 2; ++i) {
      int c = i * 256 + tid;
      int row = c >> 2, seg = c & 3;
      int gseg = seg ^ (row & 3);
      async_copy16((char*)Bs + i * 4096 + w * 1024,
                   B + (size_t)(bn0 + row) * K + k0 + gseg * 8);
    }
    __syncthreads();
    // ---- fragments + MFMA ------------------------------------------------
    half8 af[4], bf[4];
#pragma unroll
    for (int m = 0; m < 4; ++m) {
      int row = wr * 64 + m * 16 + c16;
      int off = row * 64 + ((hi4 << 4) ^ ((row & 3) << 4));
      af[m] = *(const half8*)((const char*)As + off);
    }
#pragma unroll
    for (int n = 0; n < 4; ++n) {
      int row = wc * 64 + n * 16 + c16;
      int off = row * 64 + ((hi4 << 4) ^ ((row & 3) << 4));
      bf[n] = *(const half8*)((const char*)Bs + off);
    }
#pragma unroll
    for (int m = 0; m < 4; ++m)
#pragma unroll
      for (int n = 0; n < 4; ++n)
        acc[m][n] =
            __builtin_amdgcn_mfma_f32_16x16x32_f16(af[m], bf[n], acc[m][n], 0, 0, 0);
  }
  // ---- epilogue: bias + store ------------------------------------------
#pragma unroll
  for (int n = 0; n < 4; ++n) {
    int col = bn0 + wc * 64 + n * 16 + c16;
    float bv = bias[col];
#pragma unroll
    for (int m = 0; m < 4; ++m) {
      int row0 = bm0 + wr * 64 + m * 16 + (hi4 << 2);
#pragma unroll
      for (int r = 0; r < 4; ++r) {
        float v = acc[m][n][r] + bv;
        if (OUT_F16)
          ((_Float16*)Cptr)[(size_t)(row0 + r) * N + col] = (_Float16)v;
        else
          ((float*)Cptr)[(size_t)(row0 + r) * N + col] = v;
      }
    }
  }
}

// ---------------- V transpose: V[(b s)][h*64+d] -> Vt[(b h d)][s] ---------
__global__ void transpose_v_kernel(const _Float16* __restrict__ V,
                                   _Float16* __restrict__ Vt) {
  __shared__ _Float16 tile[64][72];
  int bh = blockIdx.y;
  int b = bh >> 4, h = bh & 15;
  int s0 = blockIdx.x * 64;
  int tid = threadIdx.x;
  {
    int s = tid >> 2, dseg = tid & 3;
    const half8* src =
        (const half8*)(V + (size_t)(b * kSK + s0 + s) * kDIM + h * 64 + dseg * 16);
    half8 v0 = src[0], v1 = src[1];
#pragma unroll
    for (int j = 0; j < 8; ++j) {
      tile[s][dseg * 16 + j] = v0[j];
      tile[s][dseg * 16 + 8 + j] = v1[j];
    }
  }
  __syncthreads();
  {
    int d = tid >> 2, sseg = tid & 3;
    half8 o0, o1;
#pragma unroll
    for (int j = 0; j < 8; ++j) {
      o0[j] = tile[sseg * 16 + j][d];
      o1[j] = tile[sseg * 16 + 8 + j][d];
    }
    half8* dst = (half8*)(Vt + ((size_t)(bh * 64 + d)) * kSK + s0 + sseg * 16);
    dst[0] = o0;
    dst[1] = o1;
  }
}

// ---------------- flash attention ----------------------------------------
// block: 128 q-rows, 4 waves (32 rows each), KT=64 keys/iter.
__launch_bounds__(256, 2)
__global__ void attn_kernel(const _Float16* __restrict__ Q,
                            const _Float16* __restrict__ K,
                            const _Float16* __restrict__ Vt,
                            const unsigned* __restrict__ maskbits,
                            _Float16* __restrict__ Z) {
  __shared__ __align__(16) char smem[16384 + 128 * 72 * 2];
  _Float16* Ps = (_Float16*)(smem + 16384);  // [128][72] padded
  const int tid = threadIdx.x, lane = tid & 63, w = tid >> 6;
  const int b = blockIdx.z, h = blockIdx.y, qt0 = blockIdx.x * 128;
  const int c16 = lane & 15;
  const int hi4 = lane >> 4;
  const int row4 = hi4 << 2;

  // ---- stage Q tile [128][64] (aliases K/Vt region) ----------------------
#pragma unroll
  for (int i = 0; i < 4; ++i) {
    int c = i * 256 + tid;
    int row = c >> 3, seg = c & 7;
    int gseg = seg ^ (row & 7);
    async_copy16(smem + i * 4096 + w * 1024,
                 Q + (size_t)(b * kSQ + qt0 + row) * kDIM + h * 64 + gseg * 8);
  }
  __syncthreads();
  half8 qf[2][2];
#pragma unroll
  for (int m = 0; m < 2; ++m)
#pragma unroll
    for (int kf = 0; kf < 2; ++kf) {
      int row = w * 32 + m * 16 + c16;
      int off = row * 128 + (((kf * 4 + hi4) << 4) ^ ((row & 7) << 4));
      qf[m][kf] = *(const half8*)(smem + off);
    }
  __syncthreads();

  float m_run[8], l_run[8];
#pragma unroll
  for (int i = 0; i < 8; ++i) {
    m_run[i] = -1e30f;
    l_run[i] = 0.f;
  }
  f32x4 zacc[2][4] = {};

  const unsigned* mb = maskbits + (size_t)b * kSQ * (kSK / 32);

  for (int kt = 0; kt < kSK; kt += 64) {
    // ---- stage K [64][64] and Vt [64][64] --------------------------------
#pragma unroll
    for (int i = 0; i < 2; ++i) {
      int c = i * 256 + tid;
      int row = c >> 3, seg = c & 7;
      int gseg = seg ^ (row & 7);
      async_copy16(smem + i * 4096 + w * 1024,
                   K + (size_t)(b * kSK + kt + row) * kDIM + h * 64 + gseg * 8);
    }
#pragma unroll
    for (int i = 0; i < 2; ++i) {
      int c = i * 256 + tid;
      int row = c >> 3, seg = c & 7;
      int gseg = seg ^ (row & 7);
      async_copy16(smem + 8192 + i * 4096 + w * 1024,
                   Vt + (size_t)((b * kHEADS + h) * kHD + row) * kSK + kt + gseg * 8);
    }
    // mask words for this tile: per row, 2 words cover keys kt..kt+63
    unsigned mw[2][4][2];
#pragma unroll
    for (int m2 = 0; m2 < 2; ++m2)
#pragma unroll
      for (int r = 0; r < 4; ++r) {
        int q = qt0 + w * 32 + m2 * 16 + row4 + r;
        mw[m2][r][0] = mb[q * (kSK / 32) + (kt >> 5)];
        mw[m2][r][1] = mb[q * (kSK / 32) + (kt >> 5) + 1];
      }
    __syncthreads();

    // ---- QK^T ------------------------------------------------------------
    f32x4 s[2][4] = {};
#pragma unroll
    for (int kf = 0; kf < 2; ++kf)
#pragma unroll
      for (int n = 0; n < 4; ++n) {
        int key = n * 16 + c16;
        half8 kb = *(const half8*)(smem + key * 128 +
                                   (((kf * 4 + hi4) << 4) ^ ((key & 7) << 4)));
        s[0][n] = __builtin_amdgcn_mfma_f32_16x16x32_f16(qf[0][kf], kb, s[0][n], 0, 0, 0);
        s[1][n] = __builtin_amdgcn_mfma_f32_16x16x32_f16(qf[1][kf], kb, s[1][n], 0, 0, 0);
      }

    // ---- scale + mask + online softmax + P write -------------------------
#pragma unroll
    for (int m2 = 0; m2 < 2; ++m2)
#pragma unroll
      for (int r = 0; r < 4; ++r) {
        float v[4];
#pragma unroll
        for (int n = 0; n < 4; ++n) {
          float x = s[m2][n][r] * 0.125f;
          unsigned bits = mw[m2][r][n >> 1];
          int bit = ((n & 1) << 4) | c16;
          v[n] = ((bits >> bit) & 1u) ? x : -10000.0f;
        }
        float mx = fmaxf(fmaxf(v[0], v[1]), fmaxf(v[2], v[3]));
#pragma unroll
        for (int off = 8; off; off >>= 1) mx = fmaxf(mx, __shfl_xor(mx, off, 16));
        int idx = m2 * 4 + r;
        float mnew = fmaxf(m_run[idx], mx);
        float sf = __expf(m_run[idx] - mnew);
        int q_local = w * 32 + m2 * 16 + row4 + r;
        float rs = 0.f;
#pragma unroll
        for (int n = 0; n < 4; ++n) {
          float p = __expf(v[n] - mnew);
          rs += p;
          Ps[q_local * 72 + n * 16 + c16] = (_Float16)p;
        }
#pragma unroll
        for (int off = 8; off; off >>= 1) rs += __shfl_xor(rs, off, 16);
        l_run[idx] = l_run[idx] * sf + rs;
        m_run[idx] = mnew;
#pragma unroll
        for (int df = 0; df < 4; ++df) zacc[m2][df][r] *= sf;
      }

    // ---- PV --------------------------------------------------------------
#pragma unroll
    for (int kf2 = 0; kf2 < 2; ++kf2) {
      half8 vb[4];
#pragma unroll
      for (int df = 0; df < 4; ++df) {
        int d = df * 16 + c16;
        vb[df] = *(const half8*)(smem + 8192 + d * 128 +
                                 (((kf2 * 4 + hi4) << 4) ^ ((d & 7) << 4)));
      }
#pragma unroll
      for (int m2 = 0; m2 < 2; ++m2) {
        int q_local = w * 32 + m2 * 16 + c16;
        half8 pa = *(const half8*)((char*)Ps + q_local * 144 + (kf2 * 4 + hi4) * 16);
#pragma unroll
        for (int df = 0; df < 4; ++df)
          zacc[m2][df] =
              __builtin_amdgcn_mfma_f32_16x16x32_f16(pa, vb[df], zacc[m2][df], 0, 0, 0);
      }
    }
    __syncthreads();
  }

  // ---- epilogue: normalize, write Z (f16) --------------------------------
#pragma unroll
  for (int m2 = 0; m2 < 2; ++m2)
#pragma unroll
    for (int r = 0; r < 4; ++r) {
      int idx = m2 * 4 + r;
      float inv = 1.0f / l_run[idx];
      int q = qt0 + w * 32 + m2 * 16 + row4 + r;
#pragma unroll
      for (int df = 0; df < 4; ++df) {
        int d = df * 16 + c16;
        Z[(size_t)(b * kSQ + q) * kDIM + h * 64 + d] =
            (_Float16)(zacc[m2][df][r] * inv);
      }
    }
}

// -------------------------------------------------------------------------
extern "C" void kernel_launch(void* const* d_in, const int* in_sizes, int n_in,
                              void* d_out, int out_size, void* d_ws,
                              size_t ws_size, hipStream_t stream) {
  const float* x_q = (const float*)d_in[0];
  const float* x_k = (const float*)d_in[1];
  const float* x_v = (const float*)d_in[2];
  const int* mask = (const int*)d_in[3];
  const float* wq = (const float*)d_in[4];
  const float* bq = (const float*)d_in[5];
  const float* wk = (const float*)d_in[6];
  const float* bk = (const float*)d_in[7];
  const float* wv = (const float*)d_in[8];
  const float* bv = (const float*)d_in[9];
  const float* wo = (const float*)d_in[10];
  const float* bo = (const float*)d_in[11];

  const size_t W_ELEMS = (size_t)1024 * 1024;
  const size_t T_ELEMS = (size_t)kMTOT * kDIM;  // 8192*1024
  const size_t NEED = (4 * W_ELEMS + 5 * T_ELEMS) * 2 + (size_t)kBS * kSQ * (kSK / 32) * 4;
  if (ws_size < NEED) return;  // leaves output poisoned -> visible failure

  char* ws = (char*)d_ws;
  _Float16* Wq16 = (_Float16*)ws;
  _Float16* Wk16 = Wq16 + W_ELEMS;
  _Float16* Wv16 = Wk16 + W_ELEMS;
  _Float16* Wo16 = Wv16 + W_ELEMS;
  _Float16* Q16 = Wo16 + W_ELEMS;
  _Float16* K16 = Q16 + T_ELEMS;
  _Float16* V16 = K16 + T_ELEMS;
  _Float16* Vt16 = V16 + T_ELEMS;
  _Float16* Z16 = Vt16 + T_ELEMS;
  unsigned* mbits = (unsigned*)(Z16 + T_ELEMS);

  pack_mask_kernel<<<2048, 256, 0, stream>>>(mask, mbits);
  cvt_f32_f16_kernel<<<512, 256, 0, stream>>>(wq, Wq16, 1024 * 1024);
  cvt_f32_f16_kernel<<<512, 256, 0, stream>>>(wk, Wk16, 1024 * 1024);
  cvt_f32_f16_kernel<<<512, 256, 0, stream>>>(wv, Wv16, 1024 * 1024);
  cvt_f32_f16_kernel<<<512, 256, 0, stream>>>(wo, Wo16, 1024 * 1024);

  dim3 gg(8, 64);
  gemm_bt_kernel<true, true><<<gg, 256, 0, stream>>>(x_q, Wq16, bq, Q16, kMTOT, kDIM, kDIM);
  gemm_bt_kernel<true, true><<<gg, 256, 0, stream>>>(x_k, Wk16, bk, K16, kMTOT, kDIM, kDIM);
  gemm_bt_kernel<true, true><<<gg, 256, 0, stream>>>(x_v, Wv16, bv, V16, kMTOT, kDIM, kDIM);

  transpose_v_kernel<<<dim3(32, 64), 256, 0, stream>>>(V16, Vt16);

  attn_kernel<<<dim3(16, 16, 4), 256, 0, stream>>>(Q16, K16, Vt16, mbits, Z16);

  gemm_bt_kernel<false, false><<<gg, 256, 0, stream>>>(Z16, Wo16, bo, d_out, kMTOT, kDIM, kDIM);
}

// Round 2
// 361.772 us; speedup vs baseline: 1.2496x; 1.2496x over previous
//
#include <hip/hip_runtime.h>

#define DEVINL __device__ __forceinline__

typedef _Float16 half8 __attribute__((ext_vector_type(8)));
typedef _Float16 half4 __attribute__((ext_vector_type(4)));
typedef float f32x4 __attribute__((ext_vector_type(4)));
typedef float float4v __attribute__((ext_vector_type(4)));

static constexpr int kDIM = 1024;
static constexpr int kHEADS = 16;
static constexpr int kHD = 64;
static constexpr int kBS = 4;
static constexpr int kSQ = 2048;
static constexpr int kSK = 2048;
static constexpr int kMTOT = kBS * kSQ;  // 8192

DEVINL void async_copy16(void* lds, const void* g) {
  __builtin_amdgcn_global_load_lds(
      (__attribute__((address_space(1))) unsigned int*)(g),
      (__attribute__((address_space(3))) unsigned int*)(lds), 16, 0, 0);
}

// ---------------- mask bit-packing: mask[b][q][k] int32 -> bit per key ----
__global__ void pack_mask_kernel(const int* __restrict__ mask,
                                 unsigned* __restrict__ bits) {
  int t = blockIdx.x * blockDim.x + threadIdx.x;  // word index
  const int* p = mask + (size_t)t * 32;
  unsigned w = 0;
#pragma unroll
  for (int j = 0; j < 32; ++j) w |= (p[j] != 0 ? 1u : 0u) << j;
  bits[t] = w;
}

// ---------------- f32 -> f16 convert (weights) ---------------------------
__global__ void cvt_f32_f16_kernel(const float* __restrict__ src,
                                   _Float16* __restrict__ dst, int n) {
  int i = (blockIdx.x * blockDim.x + threadIdx.x) * 8;
  if (i >= n) return;
  float4v a0 = *(const float4v*)(src + i);
  float4v a1 = *(const float4v*)(src + i + 4);
  half8 h;
  h[0] = (_Float16)a0[0]; h[1] = (_Float16)a0[1];
  h[2] = (_Float16)a0[2]; h[3] = (_Float16)a0[3];
  h[4] = (_Float16)a1[0]; h[5] = (_Float16)a1[1];
  h[6] = (_Float16)a1[2]; h[7] = (_Float16)a1[3];
  *(half8*)(dst + i) = h;
}

// ---------------- GEMM: C[M,N] = A[M,K] @ B[N,K]^T + bias -----------------
// 128x128 tile, BK=32, 4 waves (2x2), m97 structure + source-side XOR swizzle.
template <bool A_F32, bool OUT_F16>
__launch_bounds__(256, 2)
__global__ void gemm_bt_kernel(const void* __restrict__ Aptr,
                               const _Float16* __restrict__ B,
                               const float* __restrict__ bias,
                               void* __restrict__ Cptr, int M, int N, int K) {
  __shared__ __align__(16) _Float16 As[128 * 32];
  __shared__ __align__(16) _Float16 Bs[128 * 32];
  const int tid = threadIdx.x;
  const int lane = tid & 63;
  const int w = tid >> 6;
  const int wr = w >> 1, wc = w & 1;
  const int bm0 = blockIdx.y * 128;
  const int bn0 = blockIdx.x * 128;
  const int c16 = lane & 15;
  const int hi4 = lane >> 4;

  f32x4 acc[4][4] = {};

  for (int k0 = 0; k0 < K; k0 += 32) {
    __syncthreads();
    // ---- stage A tile [128][32] f16, rows 64B, seg xor (row&3) -----------
    if (A_F32) {
      const float* A32 = (const float*)Aptr;
#pragma unroll
      for (int i = 0; i < 2; ++i) {
        int c = i * 256 + tid;
        int row = c >> 2, seg = c & 3;
        int gseg = seg ^ (row & 3);
        const float* src = A32 + (size_t)(bm0 + row) * K + k0 + gseg * 8;
        float4v a0 = *(const float4v*)src;
        float4v a1 = *(const float4v*)(src + 4);
        half8 h;
        h[0] = (_Float16)a0[0]; h[1] = (_Float16)a0[1];
        h[2] = (_Float16)a0[2]; h[3] = (_Float16)a0[3];
        h[4] = (_Float16)a1[0]; h[5] = (_Float16)a1[1];
        h[6] = (_Float16)a1[2]; h[7] = (_Float16)a1[3];
        *(half8*)((char*)As + c * 16) = h;
      }
    } else {
      const _Float16* A16 = (const _Float16*)Aptr;
#pragma unroll
      for (int i = 0; i < 2; ++i) {
        int c = i * 256 + tid;
        int row = c >> 2, seg = c & 3;
        int gseg = seg ^ (row & 3);
        async_copy16((char*)As + i * 4096 + w * 1024,
                     A16 + (size_t)(bm0 + row) * K + k0 + gseg * 8);
      }
    }
    // ---- stage B tile ----------------------------------------------------
#pragma unroll
    for (int i = 0; i < 2; ++i) {
      int c = i * 256 + tid;
      int row = c >> 2, seg = c & 3;
      int gseg = seg ^ (row & 3);
      async_copy16((char*)Bs + i * 4096 + w * 1024,
                   B + (size_t)(bn0 + row) * K + k0 + gseg * 8);
    }
    __syncthreads();
    // ---- fragments + MFMA ------------------------------------------------
    half8 af[4], bf[4];
#pragma unroll
    for (int m = 0; m < 4; ++m) {
      int row = wr * 64 + m * 16 + c16;
      int off = row * 64 + ((hi4 << 4) ^ ((row & 3) << 4));
      af[m] = *(const half8*)((const char*)As + off);
    }
#pragma unroll
    for (int n = 0; n < 4; ++n) {
      int row = wc * 64 + n * 16 + c16;
      int off = row * 64 + ((hi4 << 4) ^ ((row & 3) << 4));
      bf[n] = *(const half8*)((const char*)Bs + off);
    }
#pragma unroll
    for (int m = 0; m < 4; ++m)
#pragma unroll
      for (int n = 0; n < 4; ++n)
        acc[m][n] =
            __builtin_amdgcn_mfma_f32_16x16x32_f16(af[m], bf[n], acc[m][n], 0, 0, 0);
  }
  // ---- epilogue: bias + store ------------------------------------------
#pragma unroll
  for (int n = 0; n < 4; ++n) {
    int col = bn0 + wc * 64 + n * 16 + c16;
    float bv = bias[col];
#pragma unroll
    for (int m = 0; m < 4; ++m) {
      int row0 = bm0 + wr * 64 + m * 16 + (hi4 << 2);
#pragma unroll
      for (int r = 0; r < 4; ++r) {
        float v = acc[m][n][r] + bv;
        if (OUT_F16)
          ((_Float16*)Cptr)[(size_t)(row0 + r) * N + col] = (_Float16)v;
        else
          ((float*)Cptr)[(size_t)(row0 + r) * N + col] = v;
      }
    }
  }
}

// ---------------- V transpose: V[(b s)][h*64+d] -> Vt[(b h d)][s] ---------
__global__ void transpose_v_kernel(const _Float16* __restrict__ V,
                                   _Float16* __restrict__ Vt) {
  __shared__ _Float16 tile[64][72];
  int bh = blockIdx.y;
  int b = bh >> 4, h = bh & 15;
  int s0 = blockIdx.x * 64;
  int tid = threadIdx.x;
  {
    int s = tid >> 2, dseg = tid & 3;
    const half8* src =
        (const half8*)(V + (size_t)(b * kSK + s0 + s) * kDIM + h * 64 + dseg * 16);
    half8 v0 = src[0], v1 = src[1];
#pragma unroll
    for (int j = 0; j < 8; ++j) {
      tile[s][dseg * 16 + j] = v0[j];
      tile[s][dseg * 16 + 8 + j] = v1[j];
    }
  }
  __syncthreads();
  {
    int d = tid >> 2, sseg = tid & 3;
    half8 o0, o1;
#pragma unroll
    for (int j = 0; j < 8; ++j) {
      o0[j] = tile[sseg * 16 + j][d];
      o1[j] = tile[sseg * 16 + 8 + j][d];
    }
    half8* dst = (half8*)(Vt + ((size_t)(bh * 64 + d)) * kSK + s0 + sseg * 16);
    dst[0] = o0;
    dst[1] = o1;
  }
}

// ---------------- flash attention (swapped QK^T, lane-local softmax) ------
// block: 128 q-rows, 4 waves (32 rows each), KT=64 keys/iter.
// QK^T computed as mfma(K_frag, Q_frag) -> S^T: lane holds q = c16 (per m2
// 16-q block), keys = n*16 + hi4*4 + r in registers -> row softmax is
// lane-local + 2 shfl_xor. P goes through Ps LDS (stride 72) to become the
// PV A-operand. exp2 domain (Q pre-scaled by 0.125*log2e); deferred rescale.
__launch_bounds__(256, 2)
__global__ void attn_kernel(const _Float16* __restrict__ Q,
                            const _Float16* __restrict__ K,
                            const _Float16* __restrict__ Vt,
                            const unsigned* __restrict__ maskbits,
                            _Float16* __restrict__ Z) {
  __shared__ __align__(16) char smem[16384 + 128 * 72 * 2];
  _Float16* Ps = (_Float16*)(smem + 16384);  // [128][72] padded
  const int tid = threadIdx.x, lane = tid & 63, w = tid >> 6;
  const int b = blockIdx.z, h = blockIdx.y, qt0 = blockIdx.x * 128;
  const int c16 = lane & 15;
  const int hi4 = lane >> 4;
  const int row4 = hi4 << 2;

  // ---- stage Q tile [128][64] (aliases K/Vt region) ----------------------
#pragma unroll
  for (int i = 0; i < 4; ++i) {
    int c = i * 256 + tid;
    int row = c >> 3, seg = c & 7;
    int gseg = seg ^ (row & 7);
    async_copy16(smem + i * 4096 + w * 1024,
                 Q + (size_t)(b * kSQ + qt0 + row) * kDIM + h * 64 + gseg * 8);
  }
  __syncthreads();
  half8 qf[2][2];
#pragma unroll
  for (int m = 0; m < 2; ++m)
#pragma unroll
    for (int kf = 0; kf < 2; ++kf) {
      int row = w * 32 + m * 16 + c16;
      int off = row * 128 + (((kf * 4 + hi4) << 4) ^ ((row & 7) << 4));
      qf[m][kf] = *(const half8*)(smem + off);
      // fold softmax scale (1/8) and log2(e) into Q once
      qf[m][kf] *= (_Float16)0.18033688f;  // 0.125 * 1.44269504
    }
  __syncthreads();

  float m_run[2], l_run[2];
#pragma unroll
  for (int i = 0; i < 2; ++i) {
    m_run[i] = -1e30f;
    l_run[i] = 0.f;
  }
  f32x4 zacc[2][4] = {};

  const unsigned* mb = maskbits + (size_t)b * kSQ * (kSK / 32);

  for (int kt = 0; kt < kSK; kt += 64) {
    // ---- stage K [64][64] and Vt [64][64] --------------------------------
#pragma unroll
    for (int i = 0; i < 2; ++i) {
      int c = i * 256 + tid;
      int row = c >> 3, seg = c & 7;
      int gseg = seg ^ (row & 7);
      async_copy16(smem + i * 4096 + w * 1024,
                   K + (size_t)(b * kSK + kt + row) * kDIM + h * 64 + gseg * 8);
    }
#pragma unroll
    for (int i = 0; i < 2; ++i) {
      int c = i * 256 + tid;
      int row = c >> 3, seg = c & 7;
      int gseg = seg ^ (row & 7);
      async_copy16(smem + 8192 + i * 4096 + w * 1024,
                   Vt + (size_t)((b * kHEADS + h) * kHD + row) * kSK + kt + gseg * 8);
    }
    // ---- mask: 64 bits (this tile's keys) per q, per m2-block ------------
    unsigned long long mq[2];
#pragma unroll
    for (int m2 = 0; m2 < 2; ++m2) {
      int q = qt0 + w * 32 + m2 * 16 + c16;
      mq[m2] = *(const unsigned long long*)(mb + (size_t)q * (kSK / 32) + (kt >> 5));
    }
    __syncthreads();

    // ---- QK^T swapped: S^T[key][q], lane: q=c16, key=n*16+hi4*4+r --------
    f32x4 s[2][4] = {};
#pragma unroll
    for (int kf = 0; kf < 2; ++kf)
#pragma unroll
      for (int n = 0; n < 4; ++n) {
        int key = n * 16 + c16;
        half8 kb = *(const half8*)(smem + key * 128 +
                                   (((kf * 4 + hi4) << 4) ^ ((key & 7) << 4)));
        s[0][n] = __builtin_amdgcn_mfma_f32_16x16x32_f16(kb, qf[0][kf], s[0][n], 0, 0, 0);
        s[1][n] = __builtin_amdgcn_mfma_f32_16x16x32_f16(kb, qf[1][kf], s[1][n], 0, 0, 0);
      }

    // ---- lane-local online softmax (exp2 domain) -------------------------
#pragma unroll
    for (int m2 = 0; m2 < 2; ++m2) {
      // raw max (valid stabilizer; masked entries share score distribution)
      float t0 = fmaxf(fmaxf(s[m2][0][0], s[m2][0][1]), fmaxf(s[m2][0][2], s[m2][0][3]));
      float t1 = fmaxf(fmaxf(s[m2][1][0], s[m2][1][1]), fmaxf(s[m2][1][2], s[m2][1][3]));
      float t2 = fmaxf(fmaxf(s[m2][2][0], s[m2][2][1]), fmaxf(s[m2][2][2], s[m2][2][3]));
      float t3 = fmaxf(fmaxf(s[m2][3][0], s[m2][3][1]), fmaxf(s[m2][3][2], s[m2][3][3]));
      float mx = fmaxf(fmaxf(t0, t1), fmaxf(t2, t3));
      mx = fmaxf(mx, __shfl_xor(mx, 16));
      mx = fmaxf(mx, __shfl_xor(mx, 32));
      // deferred rescale: only when max grew past threshold (log2 domain)
      if (__any(mx > m_run[m2] + 11.5f)) {
        float mnew = fmaxf(m_run[m2], mx);
        float sf = __builtin_exp2f(m_run[m2] - mnew);
        l_run[m2] *= sf;
        m_run[m2] = mnew;
#pragma unroll
        for (int r = 0; r < 4; ++r) {
          float sfr = __shfl(sf, (lane & 48) | (row4 + r));
#pragma unroll
          for (int df = 0; df < 4; ++df) zacc[m2][df][r] *= sfr;
        }
      }
      // p = 2^(s-m) * maskbit; row-sum
      unsigned lo = (unsigned)(mq[m2] >> (hi4 * 4));
      unsigned hh = (unsigned)(mq[m2] >> (hi4 * 4 + 32));
      float rs = 0.f;
#pragma unroll
      for (int n = 0; n < 4; ++n) {
        unsigned sel = (n < 2) ? lo : hh;
#pragma unroll
        for (int r = 0; r < 4; ++r) {
          float pv = __builtin_exp2f(s[m2][n][r] - m_run[m2]);
          pv *= (float)((sel >> ((n & 1) * 16 + r)) & 1u);
          s[m2][n][r] = pv;
          rs += pv;
        }
      }
      rs += __shfl_xor(rs, 16);
      rs += __shfl_xor(rs, 32);
      l_run[m2] += rs;
      // pack 4 keys -> ds_write_b64 into Ps[q][key], stride 72
      int q_local = w * 32 + m2 * 16 + c16;
#pragma unroll
      for (int n = 0; n < 4; ++n) {
        half4 ph;
        ph[0] = (_Float16)s[m2][n][0];
        ph[1] = (_Float16)s[m2][n][1];
        ph[2] = (_Float16)s[m2][n][2];
        ph[3] = (_Float16)s[m2][n][3];
        *(half4*)((char*)Ps + q_local * 144 + n * 32 + hi4 * 8) = ph;
      }
    }

    // ---- PV --------------------------------------------------------------
#pragma unroll
    for (int kf2 = 0; kf2 < 2; ++kf2) {
      half8 vb[4];
#pragma unroll
      for (int df = 0; df < 4; ++df) {
        int d = df * 16 + c16;
        vb[df] = *(const half8*)(smem + 8192 + d * 128 +
                                 (((kf2 * 4 + hi4) << 4) ^ ((d & 7) << 4)));
      }
#pragma unroll
      for (int m2 = 0; m2 < 2; ++m2) {
        int q_local = w * 32 + m2 * 16 + c16;
        half8 pa = *(const half8*)((char*)Ps + q_local * 144 + (kf2 * 4 + hi4) * 16);
#pragma unroll
        for (int df = 0; df < 4; ++df)
          zacc[m2][df] =
              __builtin_amdgcn_mfma_f32_16x16x32_f16(pa, vb[df], zacc[m2][df], 0, 0, 0);
      }
    }
    __syncthreads();
  }

  // ---- epilogue: normalize (l lives at lane c16=q), write Z (f16) --------
#pragma unroll
  for (int m2 = 0; m2 < 2; ++m2) {
    float lval = l_run[m2];
#pragma unroll
    for (int r = 0; r < 4; ++r) {
      float lq = __shfl(lval, (lane & 48) | (row4 + r));
      float inv = 1.0f / lq;
      int q = qt0 + w * 32 + m2 * 16 + row4 + r;
#pragma unroll
      for (int df = 0; df < 4; ++df) {
        int d = df * 16 + c16;
        Z[(size_t)(b * kSQ + q) * kDIM + h * 64 + d] =
            (_Float16)(zacc[m2][df][r] * inv);
      }
    }
  }
}

// -------------------------------------------------------------------------
extern "C" void kernel_launch(void* const* d_in, const int* in_sizes, int n_in,
                              void* d_out, int out_size, void* d_ws,
                              size_t ws_size, hipStream_t stream) {
  const float* x_q = (const float*)d_in[0];
  const float* x_k = (const float*)d_in[1];
  const float* x_v = (const float*)d_in[2];
  const int* mask = (const int*)d_in[3];
  const float* wq = (const float*)d_in[4];
  const float* bq = (const float*)d_in[5];
  const float* wk = (const float*)d_in[6];
  const float* bk = (const float*)d_in[7];
  const float* wv = (const float*)d_in[8];
  const float* bv = (const float*)d_in[9];
  const float* wo = (const float*)d_in[10];
  const float* bo = (const float*)d_in[11];

  const size_t W_ELEMS = (size_t)1024 * 1024;
  const size_t T_ELEMS = (size_t)kMTOT * kDIM;  // 8192*1024
  const size_t NEED = (4 * W_ELEMS + 5 * T_ELEMS) * 2 + (size_t)kBS * kSQ * (kSK / 32) * 4;
  if (ws_size < NEED) return;  // leaves output poisoned -> visible failure

  char* ws = (char*)d_ws;
  _Float16* Wq16 = (_Float16*)ws;
  _Float16* Wk16 = Wq16 + W_ELEMS;
  _Float16* Wv16 = Wk16 + W_ELEMS;
  _Float16* Wo16 = Wv16 + W_ELEMS;
  _Float16* Q16 = Wo16 + W_ELEMS;
  _Float16* K16 = Q16 + T_ELEMS;
  _Float16* V16 = K16 + T_ELEMS;
  _Float16* Vt16 = V16 + T_ELEMS;
  _Float16* Z16 = Vt16 + T_ELEMS;
  unsigned* mbits = (unsigned*)(Z16 + T_ELEMS);

  pack_mask_kernel<<<2048, 256, 0, stream>>>(mask, mbits);
  cvt_f32_f16_kernel<<<512, 256, 0, stream>>>(wq, Wq16, 1024 * 1024);
  cvt_f32_f16_kernel<<<512, 256, 0, stream>>>(wk, Wk16, 1024 * 1024);
  cvt_f32_f16_kernel<<<512, 256, 0, stream>>>(wv, Wv16, 1024 * 1024);
  cvt_f32_f16_kernel<<<512, 256, 0, stream>>>(wo, Wo16, 1024 * 1024);

  dim3 gg(8, 64);
  gemm_bt_kernel<true, true><<<gg, 256, 0, stream>>>(x_q, Wq16, bq, Q16, kMTOT, kDIM, kDIM);
  gemm_bt_kernel<true, true><<<gg, 256, 0, stream>>>(x_k, Wk16, bk, K16, kMTOT, kDIM, kDIM);
  gemm_bt_kernel<true, true><<<gg, 256, 0, stream>>>(x_v, Wv16, bv, V16, kMTOT, kDIM, kDIM);

  transpose_v_kernel<<<dim3(32, 64), 256, 0, stream>>>(V16, Vt16);

  attn_kernel<<<dim3(16, 16, 4), 256, 0, stream>>>(Q16, K16, Vt16, mbits, Z16);

  gemm_bt_kernel<false, false><<<gg, 256, 0, stream>>>(Z16, Wo16, bo, d_out, kMTOT, kDIM, kDIM);
}